// Round 3
// baseline (1512.887 us; speedup 1.0000x reference)
//
#include <hip/hip_runtime.h>
#include <hip/hip_bf16.h>

#define NTOK 49
#define DIMC 256

typedef __attribute__((ext_vector_type(8))) short bf16x8;
typedef __attribute__((ext_vector_type(4))) float f32x4;

static __device__ __forceinline__ unsigned pk2(float a, float b) {
    union { __hip_bfloat16 h; unsigned short u; } ua, ub;
    ua.h = __float2bfloat16(a);
    ub.h = __float2bfloat16(b);
    return (unsigned)ua.u | ((unsigned)ub.u << 16);
}

static __device__ __forceinline__ bf16x8 mkfrag(unsigned w0, unsigned w1, unsigned w2, unsigned w3) {
    union { bf16x8 v; unsigned u[4]; } t;
    t.u[0] = w0; t.u[1] = w1; t.u[2] = w2; t.u[3] = w3;
    return t.v;
}

// pull both candidate halves from src lane, select by target's g>>1
static __device__ __forceinline__ unsigned sel2(unsigned lo, unsigned hi, int src, int ghi) {
    unsigned a = __shfl(lo, src);
    unsigned b = __shfl(hi, src);
    return ghi ? b : a;
}

__global__ void convert_weights(const float* __restrict__ wq, const float* __restrict__ wp,
                                unsigned short* __restrict__ wqb, unsigned short* __restrict__ wpb) {
    int i = blockIdx.x * 256 + threadIdx.x;
    if (i < 768 * 256) {
        union { __hip_bfloat16 h; unsigned short u; } t;
        t.h = __float2bfloat16(wq[i]);
        wqb[i] = t.u;
    }
    if (i < 256 * 256) {
        union { __hip_bfloat16 h; unsigned short u; } t;
        t.h = __float2bfloat16(wp[i]);
        wpb[i] = t.u;
    }
}

// One window per block, 8 waves = 512 threads, wave h owns head h end-to-end.
// LDS (48KB -> 2 blocks/CU):
//   xb [0,32768)     : x bf16 [64 t][512B rows], XOR swz ((t&7)<<4)  -> reused as attn_out [64 t][256 d] bf16
//   mb [32768,49152) : mask f32 [64 q][64 key] rows 256B, XOR ((q&7)<<4)
// All q/k/v/P fragment redistribution is in-register (4-lane-group shuffles), no LDS bounce.
__launch_bounds__(512, 4)
__global__ void win_attn_fused(const float* __restrict__ x, const float* __restrict__ mask,
                               const unsigned short* __restrict__ wqb, const float* __restrict__ bqkv,
                               const unsigned short* __restrict__ wpb, const float* __restrict__ bproj,
                               float* __restrict__ out) {
    __shared__ __align__(16) char lds[49152];
    char* const xb = lds;
    char* const mb = lds + 32768;

    const int b = blockIdx.x;
    const int tid = threadIdx.x;
    const int lane = tid & 63;
    const int wid = tid >> 6;
    const int c = lane & 15;   // fragment row/col selector
    const int g = lane >> 4;   // 4-lane-group index 0..3

    const f32x4 fzero = {0.f, 0.f, 0.f, 0.f};

    // ---------- phase 0: stage x (bf16) and mask (f32) ----------
    {
        const float* xw = x + (size_t)b * (NTOK * DIMC);
        #pragma unroll
        for (int it = 0; it < 8; ++it) {
            int idx = it * 512 + tid;         // 4096 quads of 4 floats
            int t = idx >> 6;
            int d0 = (idx & 63) * 4;
            float4 v = make_float4(0.f, 0.f, 0.f, 0.f);
            if (t < NTOK) v = *(const float4*)(xw + t * DIMC + d0);
            *(uint2*)(xb + t * 512 + ((d0 * 2) ^ ((t & 7) << 4))) =
                make_uint2(pk2(v.x, v.y), pk2(v.z, v.w));
        }
        const float* mw = mask + (size_t)b * (NTOK * NTOK);
        #pragma unroll
        for (int it = 0; it < 8; ++it) {
            int idx = it * 512 + tid;         // 4096 mask slots
            int q = idx >> 6;
            int key = idx & 63;
            float v;
            if (q < NTOK && key < NTOK) v = mw[q * NTOK + key];
            else v = (key >= NTOK) ? -1e30f : 0.f;
            *(float*)(mb + q * 256 + ((key * 4) ^ ((q & 7) << 4))) = v;
        }
    }
    __syncthreads();

    const int h = wid;
    const int srcA = c + 16 * ((2 * g) & 3);
    const int srcB = c + 16 * ((2 * g + 1) & 3);
    const int ghi = g >> 1;
    const float scale = 0.17677669529663687f;  // 32^-0.5

    // x fragment: 16B along k at row t (serves x^T B-frags and x A-frags)
    #define XFRAG(t_, kk_) (*(const bf16x8*)(xb + (t_) * 512 + ((2 * ((kk_) + 8 * g)) ^ (((t_) & 7) << 4))))

    // ---------- K^T = Wk · x^T  ->  S-MFMA A-frags kfw[it][w] ----------
    unsigned kfw[4][4], qfw[4][4];
    {
        f32x4 acc[2][4];
        #pragma unroll
        for (int md = 0; md < 2; ++md)
            #pragma unroll
            for (int j2 = 0; j2 < 4; ++j2) acc[md][j2] = fzero;
        #pragma unroll
        for (int ks = 0; ks < 8; ++ks) {
            int kk = ks * 32;
            bf16x8 bx[4];
            #pragma unroll
            for (int j2 = 0; j2 < 4; ++j2) { int t = j2 * 16 + c; bx[j2] = XFRAG(t, kk); }
            #pragma unroll
            for (int md = 0; md < 2; ++md) {
                bf16x8 wa = *(const bf16x8*)(wqb + (256 + h * 32 + md * 16 + c) * 256 + kk + 8 * g);
                #pragma unroll
                for (int j2 = 0; j2 < 4; ++j2)
                    acc[md][j2] = __builtin_amdgcn_mfma_f32_16x16x32_bf16(wa, bx[j2], acc[md][j2], 0, 0, 0);
            }
        }
        unsigned kpp[2][4][2];
        #pragma unroll
        for (int md = 0; md < 2; ++md) {
            const float* bk = bqkv + 256 + h * 32 + md * 16 + 4 * g;
            float b0 = bk[0], b1 = bk[1], b2 = bk[2], b3 = bk[3];
            #pragma unroll
            for (int j2 = 0; j2 < 4; ++j2) {
                kpp[md][j2][0] = pk2(acc[md][j2][0] + b0, acc[md][j2][1] + b1);
                kpp[md][j2][1] = pk2(acc[md][j2][2] + b2, acc[md][j2][3] + b3);
            }
        }
        #pragma unroll
        for (int it = 0; it < 4; ++it) {
            kfw[it][0] = sel2(kpp[0][it][0], kpp[1][it][0], srcA, ghi);
            kfw[it][1] = sel2(kpp[0][it][1], kpp[1][it][1], srcA, ghi);
            kfw[it][2] = sel2(kpp[0][it][0], kpp[1][it][0], srcB, ghi);
            kfw[it][3] = sel2(kpp[0][it][1], kpp[1][it][1], srcB, ghi);
        }
    }

    // ---------- Q^T = Wq · x^T (scale & bias folded) -> S-MFMA B-frags qfw[jt][w] ----------
    {
        f32x4 acc[2][4];
        #pragma unroll
        for (int md = 0; md < 2; ++md)
            #pragma unroll
            for (int j2 = 0; j2 < 4; ++j2) acc[md][j2] = fzero;
        #pragma unroll
        for (int ks = 0; ks < 8; ++ks) {
            int kk = ks * 32;
            bf16x8 bx[4];
            #pragma unroll
            for (int j2 = 0; j2 < 4; ++j2) { int t = j2 * 16 + c; bx[j2] = XFRAG(t, kk); }
            #pragma unroll
            for (int md = 0; md < 2; ++md) {
                bf16x8 wa = *(const bf16x8*)(wqb + (h * 32 + md * 16 + c) * 256 + kk + 8 * g);
                #pragma unroll
                for (int j2 = 0; j2 < 4; ++j2)
                    acc[md][j2] = __builtin_amdgcn_mfma_f32_16x16x32_bf16(wa, bx[j2], acc[md][j2], 0, 0, 0);
            }
        }
        unsigned qpp[2][4][2];
        #pragma unroll
        for (int md = 0; md < 2; ++md) {
            const float* bq = bqkv + h * 32 + md * 16 + 4 * g;
            float b0 = bq[0], b1 = bq[1], b2 = bq[2], b3 = bq[3];
            #pragma unroll
            for (int j2 = 0; j2 < 4; ++j2) {
                qpp[md][j2][0] = pk2((acc[md][j2][0] + b0) * scale, (acc[md][j2][1] + b1) * scale);
                qpp[md][j2][1] = pk2((acc[md][j2][2] + b2) * scale, (acc[md][j2][3] + b3) * scale);
            }
        }
        #pragma unroll
        for (int jt = 0; jt < 4; ++jt) {
            qfw[jt][0] = sel2(qpp[0][jt][0], qpp[1][jt][0], srcA, ghi);
            qfw[jt][1] = sel2(qpp[0][jt][1], qpp[1][jt][1], srcA, ghi);
            qfw[jt][2] = sel2(qpp[0][jt][0], qpp[1][jt][0], srcB, ghi);
            qfw[jt][3] = sel2(qpp[0][jt][1], qpp[1][jt][1], srcB, ghi);
        }
    }

    // ---------- S^T = K·Q^T + mask, softmax over keys ----------
    unsigned ppk[4][4][2];
    {
        float p[4][4][4];
        #pragma unroll
        for (int it = 0; it < 4; ++it) {
            bf16x8 ka = mkfrag(kfw[it][0], kfw[it][1], kfw[it][2], kfw[it][3]);
            #pragma unroll
            for (int jt = 0; jt < 4; ++jt) {
                bf16x8 qb_ = mkfrag(qfw[jt][0], qfw[jt][1], qfw[jt][2], qfw[jt][3]);
                f32x4 s = __builtin_amdgcn_mfma_f32_16x16x32_bf16(ka, qb_, fzero, 0, 0, 0);
                int q = jt * 16 + c;
                int key0 = it * 16 + g * 4;
                f32x4 mv = *(const f32x4*)(mb + q * 256 + ((key0 * 4) ^ ((q & 7) << 4)));
                #pragma unroll
                for (int r = 0; r < 4; ++r)
                    p[it][jt][r] = s[r] + mv[r];
            }
        }
        // softmax over keys; lanes {c, c+16, c+32, c+48} share a query column
        #pragma unroll
        for (int jt = 0; jt < 4; ++jt) {
            float m = -1e30f;
            #pragma unroll
            for (int it = 0; it < 4; ++it)
                #pragma unroll
                for (int r = 0; r < 4; ++r)
                    m = fmaxf(m, p[it][jt][r]);
            m = fmaxf(m, __shfl_xor(m, 16));
            m = fmaxf(m, __shfl_xor(m, 32));
            float ssum = 0.f;
            #pragma unroll
            for (int it = 0; it < 4; ++it)
                #pragma unroll
                for (int r = 0; r < 4; ++r) {
                    float e = __expf(p[it][jt][r] - m);
                    p[it][jt][r] = e;
                    ssum += e;
                }
            ssum += __shfl_xor(ssum, 16);
            ssum += __shfl_xor(ssum, 32);
            float inv = 1.0f / ssum;
            #pragma unroll
            for (int it = 0; it < 4; ++it)
                #pragma unroll
                for (int r = 0; r < 4; ++r)
                    p[it][jt][r] *= inv;
        }
        #pragma unroll
        for (int it = 0; it < 4; ++it)
            #pragma unroll
            for (int jt = 0; jt < 4; ++jt) {
                ppk[it][jt][0] = pk2(p[it][jt][0], p[it][jt][1]);
                ppk[it][jt][1] = pk2(p[it][jt][2], p[it][jt][3]);
            }
    }

    // ---------- V = x · Wv  (C rows = key, cols = d) ----------
    unsigned vpp[4][2][2];
    {
        f32x4 acc[4][2];
        #pragma unroll
        for (int mt = 0; mt < 4; ++mt)
            #pragma unroll
            for (int j2 = 0; j2 < 2; ++j2) acc[mt][j2] = fzero;
        #pragma unroll
        for (int ks = 0; ks < 8; ++ks) {
            int kk = ks * 32;
            bf16x8 ax[4];
            #pragma unroll
            for (int mt = 0; mt < 4; ++mt) { int t = mt * 16 + c; ax[mt] = XFRAG(t, kk); }
            #pragma unroll
            for (int j2 = 0; j2 < 2; ++j2) {
                bf16x8 wb = *(const bf16x8*)(wqb + (512 + h * 32 + j2 * 16 + c) * 256 + kk + 8 * g);
                #pragma unroll
                for (int mt = 0; mt < 4; ++mt)
                    acc[mt][j2] = __builtin_amdgcn_mfma_f32_16x16x32_bf16(ax[mt], wb, acc[mt][j2], 0, 0, 0);
            }
        }
        float bv0 = bqkv[512 + h * 32 + c];
        float bv1 = bqkv[512 + h * 32 + 16 + c];
        #pragma unroll
        for (int mt = 0; mt < 4; ++mt) {
            vpp[mt][0][0] = pk2(acc[mt][0][0] + bv0, acc[mt][0][1] + bv0);
            vpp[mt][0][1] = pk2(acc[mt][0][2] + bv0, acc[mt][0][3] + bv0);
            vpp[mt][1][0] = pk2(acc[mt][1][0] + bv1, acc[mt][1][1] + bv1);
            vpp[mt][1][1] = pk2(acc[mt][1][2] + bv1, acc[mt][1][3] + bv1);
        }
    }

    // ---------- PV: out^T = V^T · P^T ----------
    f32x4 oacc[2][4];
    #pragma unroll
    for (int dt = 0; dt < 2; ++dt)
        #pragma unroll
        for (int jt = 0; jt < 4; ++jt) oacc[dt][jt] = fzero;
    #pragma unroll
    for (int kh = 0; kh < 2; ++kh) {
        bf16x8 vf[2];
        #pragma unroll
        for (int dt = 0; dt < 2; ++dt)
            vf[dt] = mkfrag(sel2(vpp[2 * kh][dt][0], vpp[2 * kh + 1][dt][0], srcA, ghi),
                            sel2(vpp[2 * kh][dt][1], vpp[2 * kh + 1][dt][1], srcA, ghi),
                            sel2(vpp[2 * kh][dt][0], vpp[2 * kh + 1][dt][0], srcB, ghi),
                            sel2(vpp[2 * kh][dt][1], vpp[2 * kh + 1][dt][1], srcB, ghi));
        #pragma unroll
        for (int jt = 0; jt < 4; ++jt) {
            bf16x8 pf = mkfrag(sel2(ppk[2 * kh][jt][0], ppk[2 * kh + 1][jt][0], srcA, ghi),
                               sel2(ppk[2 * kh][jt][1], ppk[2 * kh + 1][jt][1], srcA, ghi),
                               sel2(ppk[2 * kh][jt][0], ppk[2 * kh + 1][jt][0], srcB, ghi),
                               sel2(ppk[2 * kh][jt][1], ppk[2 * kh + 1][jt][1], srcB, ghi));
            #pragma unroll
            for (int dt = 0; dt < 2; ++dt)
                oacc[dt][jt] = __builtin_amdgcn_mfma_f32_16x16x32_bf16(vf[dt], pf, oacc[dt][jt], 0, 0, 0);
        }
    }

    __syncthreads();   // all xb (x) reads complete -> reuse xb as attn_out

    // attn_out -> xb region as [64 t][256 d] bf16, 512B rows
    #pragma unroll
    for (int dt = 0; dt < 2; ++dt) {
        #pragma unroll
        for (int jt = 0; jt < 4; ++jt) {
            int q = jt * 16 + c;
            int d0 = h * 32 + dt * 16 + 4 * g;
            f32x4 v = oacc[dt][jt];
            *(uint2*)(xb + q * 512 + ((2 * d0) ^ ((q & 7) << 4))) =
                make_uint2(pk2(v[0], v[1]), pk2(v[2], v[3]));
        }
    }
    __syncthreads();

    // ---------- proj GEMM (M=64, N=256, K=256) + bias ----------
    {
        f32x4 pacc[2][4];
        #pragma unroll
        for (int j = 0; j < 2; ++j)
            #pragma unroll
            for (int mt = 0; mt < 4; ++mt) pacc[j][mt] = fzero;

        #pragma unroll
        for (int ks = 0; ks < 8; ++ks) {
            int kk = ks * 32;
            bf16x8 af[4];
            #pragma unroll
            for (int mt = 0; mt < 4; ++mt) { int t = mt * 16 + c; af[mt] = XFRAG(t, kk); }
            #pragma unroll
            for (int j = 0; j < 2; ++j) {
                int o = (wid * 2 + j) * 16 + c;
                bf16x8 bfr = *(const bf16x8*)(wpb + (size_t)o * 256 + kk + 8 * g);
                #pragma unroll
                for (int mt = 0; mt < 4; ++mt)
                    pacc[j][mt] = __builtin_amdgcn_mfma_f32_16x16x32_bf16(af[mt], bfr, pacc[j][mt], 0, 0, 0);
            }
        }
        float* ob = out + (size_t)b * (NTOK * DIMC);
        #pragma unroll
        for (int j = 0; j < 2; ++j) {
            int o = (wid * 2 + j) * 16 + c;
            float bias = bproj[o];
            #pragma unroll
            for (int mt = 0; mt < 4; ++mt) {
                #pragma unroll
                for (int r = 0; r < 4; ++r) {
                    int t = mt * 16 + g * 4 + r;
                    if (t < NTOK) ob[t * DIMC + o] = pacc[j][mt][r] + bias;
                }
            }
        }
    }
    #undef XFRAG
}

extern "C" void kernel_launch(void* const* d_in, const int* in_sizes, int n_in,
                              void* d_out, int out_size, void* d_ws, size_t ws_size,
                              hipStream_t stream) {
    const float* x    = (const float*)d_in[0];
    const float* mask = (const float*)d_in[1];
    const float* wq   = (const float*)d_in[2];
    const float* bq   = (const float*)d_in[3];
    const float* wp   = (const float*)d_in[4];
    const float* bp   = (const float*)d_in[5];
    float* o = (float*)d_out;

    unsigned short* wqb = (unsigned short*)d_ws;          // 768*256 bf16
    unsigned short* wpb = wqb + 768 * 256;                // 256*256 bf16

    convert_weights<<<768, 256, 0, stream>>>(wq, wp, wqb, wpb);
    win_attn_fused<<<8192, 512, 0, stream>>>(x, mask, wqb, bq, wpb, bp, o);
}

// Round 4
// 884.109 us; speedup vs baseline: 1.7112x; 1.7112x over previous
//
#include <hip/hip_runtime.h>
#include <hip/hip_bf16.h>

#define NTOK 49
#define DIMC 256

typedef __attribute__((ext_vector_type(8))) short bf16x8;
typedef __attribute__((ext_vector_type(4))) float f32x4;

static __device__ __forceinline__ unsigned pk2(float a, float b) {
    union { __hip_bfloat16 h; unsigned short u; } ua, ub;
    ua.h = __float2bfloat16(a);
    ub.h = __float2bfloat16(b);
    return (unsigned)ua.u | ((unsigned)ub.u << 16);
}

static __device__ __forceinline__ bf16x8 mkfrag(unsigned w0, unsigned w1, unsigned w2, unsigned w3) {
    union { bf16x8 v; unsigned u[4]; } t;
    t.u[0] = w0; t.u[1] = w1; t.u[2] = w2; t.u[3] = w3;
    return t.v;
}

// pull both candidate halves from src lane, select by target's g>>1
static __device__ __forceinline__ unsigned sel2(unsigned lo, unsigned hi, int src, int ghi) {
    unsigned a = __shfl(lo, src);
    unsigned b = __shfl(hi, src);
    return ghi ? b : a;
}

__global__ void convert_weights(const float* __restrict__ wq, const float* __restrict__ wp,
                                unsigned short* __restrict__ wqb, unsigned short* __restrict__ wpb) {
    int i = blockIdx.x * 256 + threadIdx.x;
    if (i < 768 * 256) {
        union { __hip_bfloat16 h; unsigned short u; } t;
        t.h = __float2bfloat16(wq[i]);
        wqb[i] = t.u;
    }
    if (i < 256 * 256) {
        union { __hip_bfloat16 h; unsigned short u; } t;
        t.h = __float2bfloat16(wp[i]);
        wpb[i] = t.u;
    }
}

// One window per block, 8 waves = 512 threads, wave h owns head h end-to-end.
// LDS (48KB):
//   xb [0,32768)     : x bf16 [64 t][512B rows], XOR swz ((t&7)<<4) -> reused as attn_out [64 t][256 d] bf16
//   mb [32768,49152) : mask f32 [64 q][64 key] rows 256B, XOR ((q&7)<<4)
// All q/k/v/P fragment redistribution in-register (4-lane-group shuffles).
// NOTE: 2nd launch_bounds arg observed to act as min-BLOCKS/CU on this toolchain:
//   (512,2) -> 16 waves/CU -> 128-VGPR cap (round-2 evidence); (512,4) caused 64-VGPR spill disaster.
__launch_bounds__(512, 2)
__global__ void win_attn_fused(const float* __restrict__ x, const float* __restrict__ mask,
                               const unsigned short* __restrict__ wqb, const float* __restrict__ bqkv,
                               const unsigned short* __restrict__ wpb, const float* __restrict__ bproj,
                               float* __restrict__ out) {
    __shared__ __align__(16) char lds[49152];
    char* const xb = lds;
    char* const mb = lds + 32768;

    const int b = blockIdx.x;
    const int tid = threadIdx.x;
    const int lane = tid & 63;
    const int wid = tid >> 6;
    const int c = lane & 15;   // fragment row/col selector
    const int g = lane >> 4;   // 4-lane-group index 0..3

    const f32x4 fzero = {0.f, 0.f, 0.f, 0.f};

    // ---------- phase 0: stage x (bf16) and mask (f32) ----------
    {
        const float* xw = x + (size_t)b * (NTOK * DIMC);
        #pragma unroll
        for (int it = 0; it < 8; ++it) {
            int idx = it * 512 + tid;         // 4096 quads of 4 floats
            int t = idx >> 6;
            int d0 = (idx & 63) * 4;
            float4 v = make_float4(0.f, 0.f, 0.f, 0.f);
            if (t < NTOK) v = *(const float4*)(xw + t * DIMC + d0);
            *(uint2*)(xb + t * 512 + ((d0 * 2) ^ ((t & 7) << 4))) =
                make_uint2(pk2(v.x, v.y), pk2(v.z, v.w));
        }
        const float* mw = mask + (size_t)b * (NTOK * NTOK);
        #pragma unroll
        for (int it = 0; it < 8; ++it) {
            int idx = it * 512 + tid;         // 4096 mask slots
            int q = idx >> 6;
            int key = idx & 63;
            float v;
            if (q < NTOK && key < NTOK) v = mw[q * NTOK + key];
            else v = (key >= NTOK) ? -1e30f : 0.f;
            *(float*)(mb + q * 256 + ((key * 4) ^ ((q & 7) << 4))) = v;
        }
    }
    __syncthreads();

    const int h = wid;
    const int srcA = c + 16 * ((2 * g) & 3);
    const int srcB = c + 16 * ((2 * g + 1) & 3);
    const int ghi = g >> 1;
    const float scale = 0.17677669529663687f;  // 32^-0.5

    // x fragment: 16B along k at row t (serves x^T B-frags and x A-frags)
    #define XFRAG(t_, kk_) (*(const bf16x8*)(xb + (t_) * 512 + ((2 * ((kk_) + 8 * g)) ^ (((t_) & 7) << 4))))

    // ---------- V = x · Wv  ->  PV A-frags vf[kh][dt] (vpp dies immediately) ----------
    bf16x8 vf[2][2];
    {
        f32x4 acc[4][2];
        #pragma unroll
        for (int mt = 0; mt < 4; ++mt)
            #pragma unroll
            for (int j2 = 0; j2 < 2; ++j2) acc[mt][j2] = fzero;
        #pragma unroll
        for (int ks = 0; ks < 8; ++ks) {
            int kk = ks * 32;
            bf16x8 ax[4];
            #pragma unroll
            for (int mt = 0; mt < 4; ++mt) { int t = mt * 16 + c; ax[mt] = XFRAG(t, kk); }
            #pragma unroll
            for (int j2 = 0; j2 < 2; ++j2) {
                bf16x8 wb = *(const bf16x8*)(wqb + (512 + h * 32 + j2 * 16 + c) * 256 + kk + 8 * g);
                #pragma unroll
                for (int mt = 0; mt < 4; ++mt)
                    acc[mt][j2] = __builtin_amdgcn_mfma_f32_16x16x32_bf16(ax[mt], wb, acc[mt][j2], 0, 0, 0);
            }
        }
        float bv0 = bqkv[512 + h * 32 + c];
        float bv1 = bqkv[512 + h * 32 + 16 + c];
        unsigned vpp[4][2][2];
        #pragma unroll
        for (int mt = 0; mt < 4; ++mt) {
            vpp[mt][0][0] = pk2(acc[mt][0][0] + bv0, acc[mt][0][1] + bv0);
            vpp[mt][0][1] = pk2(acc[mt][0][2] + bv0, acc[mt][0][3] + bv0);
            vpp[mt][1][0] = pk2(acc[mt][1][0] + bv1, acc[mt][1][1] + bv1);
            vpp[mt][1][1] = pk2(acc[mt][1][2] + bv1, acc[mt][1][3] + bv1);
        }
        #pragma unroll
        for (int kh = 0; kh < 2; ++kh)
            #pragma unroll
            for (int dt = 0; dt < 2; ++dt)
                vf[kh][dt] = mkfrag(sel2(vpp[2 * kh][dt][0], vpp[2 * kh + 1][dt][0], srcA, ghi),
                                    sel2(vpp[2 * kh][dt][1], vpp[2 * kh + 1][dt][1], srcA, ghi),
                                    sel2(vpp[2 * kh][dt][0], vpp[2 * kh + 1][dt][0], srcB, ghi),
                                    sel2(vpp[2 * kh][dt][1], vpp[2 * kh + 1][dt][1], srcB, ghi));
    }

    // ---------- K^T = Wk · x^T  ->  S-MFMA A-frags ka[it] ----------
    bf16x8 ka[4];
    {
        f32x4 acc[2][4];
        #pragma unroll
        for (int md = 0; md < 2; ++md)
            #pragma unroll
            for (int j2 = 0; j2 < 4; ++j2) acc[md][j2] = fzero;
        #pragma unroll
        for (int ks = 0; ks < 8; ++ks) {
            int kk = ks * 32;
            bf16x8 bx[4];
            #pragma unroll
            for (int j2 = 0; j2 < 4; ++j2) { int t = j2 * 16 + c; bx[j2] = XFRAG(t, kk); }
            #pragma unroll
            for (int md = 0; md < 2; ++md) {
                bf16x8 wa = *(const bf16x8*)(wqb + (256 + h * 32 + md * 16 + c) * 256 + kk + 8 * g);
                #pragma unroll
                for (int j2 = 0; j2 < 4; ++j2)
                    acc[md][j2] = __builtin_amdgcn_mfma_f32_16x16x32_bf16(wa, bx[j2], acc[md][j2], 0, 0, 0);
            }
        }
        unsigned kpp[2][4][2];
        #pragma unroll
        for (int md = 0; md < 2; ++md) {
            const float* bk = bqkv + 256 + h * 32 + md * 16 + 4 * g;
            float b0 = bk[0], b1 = bk[1], b2 = bk[2], b3 = bk[3];
            #pragma unroll
            for (int j2 = 0; j2 < 4; ++j2) {
                kpp[md][j2][0] = pk2(acc[md][j2][0] + b0, acc[md][j2][1] + b1);
                kpp[md][j2][1] = pk2(acc[md][j2][2] + b2, acc[md][j2][3] + b3);
            }
        }
        #pragma unroll
        for (int it = 0; it < 4; ++it)
            ka[it] = mkfrag(sel2(kpp[0][it][0], kpp[1][it][0], srcA, ghi),
                            sel2(kpp[0][it][1], kpp[1][it][1], srcA, ghi),
                            sel2(kpp[0][it][0], kpp[1][it][0], srcB, ghi),
                            sel2(kpp[0][it][1], kpp[1][it][1], srcB, ghi));
    }

    // ---------- Q^T = Wq · x^T (scale+bias folded) -> S-MFMA B-frags qf[jt] ----------
    bf16x8 qf[4];
    {
        f32x4 acc[2][4];
        #pragma unroll
        for (int md = 0; md < 2; ++md)
            #pragma unroll
            for (int j2 = 0; j2 < 4; ++j2) acc[md][j2] = fzero;
        #pragma unroll
        for (int ks = 0; ks < 8; ++ks) {
            int kk = ks * 32;
            bf16x8 bx[4];
            #pragma unroll
            for (int j2 = 0; j2 < 4; ++j2) { int t = j2 * 16 + c; bx[j2] = XFRAG(t, kk); }
            #pragma unroll
            for (int md = 0; md < 2; ++md) {
                bf16x8 wa = *(const bf16x8*)(wqb + (h * 32 + md * 16 + c) * 256 + kk + 8 * g);
                #pragma unroll
                for (int j2 = 0; j2 < 4; ++j2)
                    acc[md][j2] = __builtin_amdgcn_mfma_f32_16x16x32_bf16(wa, bx[j2], acc[md][j2], 0, 0, 0);
            }
        }
        unsigned qpp[2][4][2];
        #pragma unroll
        for (int md = 0; md < 2; ++md) {
            const float* bq = bqkv + h * 32 + md * 16 + 4 * g;
            float b0 = bq[0], b1 = bq[1], b2 = bq[2], b3 = bq[3];
            #pragma unroll
            for (int j2 = 0; j2 < 4; ++j2) {
                qpp[md][j2][0] = pk2((acc[md][j2][0] + b0) * scale, (acc[md][j2][1] + b1) * scale);
                qpp[md][j2][1] = pk2((acc[md][j2][2] + b2) * scale, (acc[md][j2][3] + b3) * scale);
            }
        }
        #pragma unroll
        for (int jt = 0; jt < 4; ++jt)
            qf[jt] = mkfrag(sel2(qpp[0][jt][0], qpp[1][jt][0], srcA, ghi),
                            sel2(qpp[0][jt][1], qpp[1][jt][1], srcA, ghi),
                            sel2(qpp[0][jt][0], qpp[1][jt][0], srcB, ghi),
                            sel2(qpp[0][jt][1], qpp[1][jt][1], srcB, ghi));
    }

    // ---------- per query-tile: S^T = K·Q^T + mask, softmax, PV ----------
    f32x4 oacc[2][4];
    #pragma unroll
    for (int dt = 0; dt < 2; ++dt)
        #pragma unroll
        for (int jt = 0; jt < 4; ++jt) oacc[dt][jt] = fzero;

    #pragma unroll
    for (int jt = 0; jt < 4; ++jt) {
        float p[4][4];
        int q = jt * 16 + c;
        #pragma unroll
        for (int it = 0; it < 4; ++it) {
            f32x4 s = __builtin_amdgcn_mfma_f32_16x16x32_bf16(ka[it], qf[jt], fzero, 0, 0, 0);
            int key0 = it * 16 + g * 4;
            f32x4 mv = *(const f32x4*)(mb + q * 256 + ((key0 * 4) ^ ((q & 7) << 4)));
            #pragma unroll
            for (int r = 0; r < 4; ++r)
                p[it][r] = s[r] + mv[r];
        }
        // softmax over keys; lanes {c, c+16, c+32, c+48} share a query column
        float m = -1e30f;
        #pragma unroll
        for (int it = 0; it < 4; ++it)
            #pragma unroll
            for (int r = 0; r < 4; ++r)
                m = fmaxf(m, p[it][r]);
        m = fmaxf(m, __shfl_xor(m, 16));
        m = fmaxf(m, __shfl_xor(m, 32));
        float ssum = 0.f;
        #pragma unroll
        for (int it = 0; it < 4; ++it)
            #pragma unroll
            for (int r = 0; r < 4; ++r) {
                float e = __expf(p[it][r] - m);
                p[it][r] = e;
                ssum += e;
            }
        ssum += __shfl_xor(ssum, 16);
        ssum += __shfl_xor(ssum, 32);
        float inv = 1.0f / ssum;
        unsigned pq[4][2];
        #pragma unroll
        for (int it = 0; it < 4; ++it) {
            pq[it][0] = pk2(p[it][0] * inv, p[it][1] * inv);
            pq[it][1] = pk2(p[it][2] * inv, p[it][3] * inv);
        }
        // PV: out^T(:, this q-tile) += V^T · P^T
        #pragma unroll
        for (int kh = 0; kh < 2; ++kh) {
            bf16x8 pf = mkfrag(sel2(pq[2 * kh][0], pq[2 * kh + 1][0], srcA, ghi),
                               sel2(pq[2 * kh][1], pq[2 * kh + 1][1], srcA, ghi),
                               sel2(pq[2 * kh][0], pq[2 * kh + 1][0], srcB, ghi),
                               sel2(pq[2 * kh][1], pq[2 * kh + 1][1], srcB, ghi));
            #pragma unroll
            for (int dt = 0; dt < 2; ++dt)
                oacc[dt][jt] = __builtin_amdgcn_mfma_f32_16x16x32_bf16(vf[kh][dt], pf, oacc[dt][jt], 0, 0, 0);
        }
    }

    __syncthreads();   // all xb (x) reads complete -> reuse xb as attn_out

    // attn_out -> xb region as [64 t][256 d] bf16, 512B rows
    #pragma unroll
    for (int dt = 0; dt < 2; ++dt) {
        #pragma unroll
        for (int jt = 0; jt < 4; ++jt) {
            int q = jt * 16 + c;
            int d0 = h * 32 + dt * 16 + 4 * g;
            f32x4 v = oacc[dt][jt];
            *(uint2*)(xb + q * 512 + ((2 * d0) ^ ((q & 7) << 4))) =
                make_uint2(pk2(v[0], v[1]), pk2(v[2], v[3]));
        }
    }
    __syncthreads();

    // ---------- proj GEMM (M=64, N=256, K=256) + bias ----------
    {
        f32x4 pacc[2][4];
        #pragma unroll
        for (int j = 0; j < 2; ++j)
            #pragma unroll
            for (int mt = 0; mt < 4; ++mt) pacc[j][mt] = fzero;

        #pragma unroll
        for (int ks = 0; ks < 8; ++ks) {
            int kk = ks * 32;
            bf16x8 af[4];
            #pragma unroll
            for (int mt = 0; mt < 4; ++mt) { int t = mt * 16 + c; af[mt] = XFRAG(t, kk); }
            #pragma unroll
            for (int j = 0; j < 2; ++j) {
                int o = (wid * 2 + j) * 16 + c;
                bf16x8 bfr = *(const bf16x8*)(wpb + (size_t)o * 256 + kk + 8 * g);
                #pragma unroll
                for (int mt = 0; mt < 4; ++mt)
                    pacc[j][mt] = __builtin_amdgcn_mfma_f32_16x16x32_bf16(af[mt], bfr, pacc[j][mt], 0, 0, 0);
            }
        }
        float* ob = out + (size_t)b * (NTOK * DIMC);
        #pragma unroll
        for (int j = 0; j < 2; ++j) {
            int o = (wid * 2 + j) * 16 + c;
            float bias = bproj[o];
            #pragma unroll
            for (int mt = 0; mt < 4; ++mt) {
                #pragma unroll
                for (int r = 0; r < 4; ++r) {
                    int t = mt * 16 + g * 4 + r;
                    if (t < NTOK) ob[t * DIMC + o] = pacc[j][mt][r] + bias;
                }
            }
        }
    }
    #undef XFRAG
}

extern "C" void kernel_launch(void* const* d_in, const int* in_sizes, int n_in,
                              void* d_out, int out_size, void* d_ws, size_t ws_size,
                              hipStream_t stream) {
    const float* x    = (const float*)d_in[0];
    const float* mask = (const float*)d_in[1];
    const float* wq   = (const float*)d_in[2];
    const float* bq   = (const float*)d_in[3];
    const float* wp   = (const float*)d_in[4];
    const float* bp   = (const float*)d_in[5];
    float* o = (float*)d_out;

    unsigned short* wqb = (unsigned short*)d_ws;          // 768*256 bf16
    unsigned short* wpb = wqb + 768 * 256;                // 256*256 bf16

    convert_weights<<<768, 256, 0, stream>>>(wq, wp, wqb, wpb);
    win_attn_fused<<<8192, 512, 0, stream>>>(x, mask, wqb, bq, wpb, bp, o);
}